// Round 1
// baseline (289.805 us; speedup 1.0000x reference)
//
#include <hip/hip_runtime.h>

#define BB 2
#define LL 1024
#define DD 1024
#define HH 16
#define HD 64
#define CH 64
#define NC (LL/CH)
#define EPSF 1e-8f

// ---------------- GEMM: Y[m,n] = sum_k X[m,k] * W[n,k]  (both row-major along k)
// M = B*L = 2048, N = K = 1024. 64x64 tiles, 256 threads, 4x4 microtile.
__global__ __launch_bounds__(256) void gemm_nt(const float* __restrict__ X,
                                               const float* __restrict__ Wq,
                                               const float* __restrict__ Wv,
                                               float* __restrict__ Qr,
                                               float* __restrict__ Vr)
{
    const int M = BB*LL, N = DD, K = DD;
    const float* W = (blockIdx.z == 0) ? Wq : Wv;
    float* Y = (blockIdx.z == 0) ? Qr : Vr;
    __shared__ float Xs[64][65];
    __shared__ float Ws[64][65];
    int tid = threadIdx.x;
    int tx = tid & 15, ty = tid >> 4;
    int m0 = blockIdx.y * 64, n0 = blockIdx.x * 64;
    float acc[4][4] = {};
    for (int k0 = 0; k0 < K; k0 += 64) {
        #pragma unroll
        for (int t = 0; t < 16; ++t) {
            int e = tid + t * 256;
            int r = e >> 6, cc = e & 63;
            Xs[r][cc] = X[(size_t)(m0 + r) * K + k0 + cc];
            Ws[r][cc] = W[(size_t)(n0 + r) * K + k0 + cc];
        }
        __syncthreads();
        #pragma unroll 8
        for (int k = 0; k < 64; ++k) {
            float a[4], bb[4];
            #pragma unroll
            for (int j = 0; j < 4; ++j) { a[j] = Xs[ty*4+j][k]; bb[j] = Ws[tx*4+j][k]; }
            #pragma unroll
            for (int p = 0; p < 4; ++p)
                #pragma unroll
                for (int q = 0; q < 4; ++q)
                    acc[p][q] += a[p] * bb[q];
        }
        __syncthreads();
    }
    #pragma unroll
    for (int p = 0; p < 4; ++p)
        #pragma unroll
        for (int q = 0; q < 4; ++q)
            Y[(size_t)(m0 + ty*4+p) * N + n0 + tx*4+q] = acc[p][q];
    (void)M;
}

// ---------------- RMSNorm (in place) over last dim d=64, per-head weight
__global__ __launch_bounds__(256) void rmsnorm_k(float* __restrict__ Q,
                                                 float* __restrict__ V,
                                                 const float* __restrict__ qw,
                                                 const float* __restrict__ vw)
{
    float* Y = (blockIdx.y == 0) ? Q : V;
    const float* w = (blockIdx.y == 0) ? qw : vw;
    int row = blockIdx.x * 4 + (threadIdx.x >> 6);   // row over B*L*H
    int lane = threadIdx.x & 63;
    int h = row % HH;
    size_t idx = (size_t)row * 64 + lane;
    float x = Y[idx];
    float ss = x * x;
    #pragma unroll
    for (int off = 32; off >= 1; off >>= 1) ss += __shfl_xor(ss, off, 64);
    float scale = rsqrtf(ss * (1.0f/64.0f) + EPSF);
    Y[idx] = x * scale * w[h * 64 + lane];
}

// ---------------- per-chunk KV outer-product sums: S_c = K_c^T V_c (64x64)
__global__ __launch_bounds__(256) void chunk_kv(const float* __restrict__ X,
                                                const float* __restrict__ V,
                                                float* __restrict__ S)
{
    int c = blockIdx.x % NC;
    int bh = blockIdx.x / NC;
    int h = bh % HH, b = bh / HH;
    __shared__ float Ks[64][65], Vs[64][65];
    int tid = threadIdx.x;
    #pragma unroll
    for (int t = 0; t < 16; ++t) {
        int e = tid + t * 256;
        int i = e >> 6, j = e & 63;
        size_t base = ((size_t)(b*LL + c*64 + i) * DD) + h*64 + j;
        Ks[i][j] = X[base];   // K is raw X reshaped
        Vs[i][j] = V[base];
    }
    __syncthreads();
    int tx = tid & 15, ty = tid >> 4;
    float acc[4][4] = {};
    #pragma unroll 8
    for (int i = 0; i < 64; ++i) {
        float a[4], bb[4];
        #pragma unroll
        for (int j = 0; j < 4; ++j) { a[j] = Ks[i][ty*4+j]; bb[j] = Vs[i][tx*4+j]; }
        #pragma unroll
        for (int p = 0; p < 4; ++p)
            #pragma unroll
            for (int q = 0; q < 4; ++q)
                acc[p][q] += a[p] * bb[q];
    }
    float* Sp = S + (size_t)blockIdx.x * 4096;
    #pragma unroll
    for (int p = 0; p < 4; ++p)
        #pragma unroll
        for (int q = 0; q < 4; ++q)
            Sp[(ty*4+p) * 64 + tx*4+q] = acc[p][q];
}

// ---------------- in-place exclusive cumsum of chunk states along chunks
__global__ __launch_bounds__(256) void cumsum_k(float* __restrict__ S)
{
    float* base = S + (size_t)blockIdx.x * NC * 4096;
    #pragma unroll
    for (int j = 0; j < 16; ++j) {
        int p = threadIdx.x + j * 256;
        float run = 0.f;
        for (int cc = 0; cc < NC; ++cc) {
            float v = base[cc*4096 + p];
            base[cc*4096 + p] = run;
            run += v;
        }
    }
}

// ---------------- out = Q @ S_prefix + tril(Q K^T) @ V, per chunk
__global__ __launch_bounds__(256) void out_k(const float* __restrict__ X,
                                             const float* __restrict__ Q,
                                             const float* __restrict__ V,
                                             const float* __restrict__ S,
                                             float* __restrict__ out)
{
    int c = blockIdx.x % NC;
    int bh = blockIdx.x / NC;
    int h = bh % HH, b = bh / HH;
    __shared__ float Qs[64][65], KSs[64][65], Vs[64][65], As[64][65];
    int tid = threadIdx.x;
    #pragma unroll
    for (int t = 0; t < 16; ++t) {
        int e = tid + t * 256;
        int i = e >> 6, j = e & 63;
        size_t base = ((size_t)(b*LL + c*64 + i) * DD) + h*64 + j;
        Qs[i][j]  = Q[base];
        KSs[i][j] = X[base];   // K chunk
        Vs[i][j]  = V[base];
    }
    __syncthreads();
    int tx = tid & 15, ty = tid >> 4;
    // A[l][lp] = (lp<=l) ? dot(Q[l], K[lp]) : 0
    {
        float acc[4][4] = {};
        #pragma unroll 8
        for (int k = 0; k < 64; ++k) {
            float a[4], bb[4];
            #pragma unroll
            for (int j = 0; j < 4; ++j) { a[j] = Qs[ty*4+j][k]; bb[j] = KSs[tx*4+j][k]; }
            #pragma unroll
            for (int p = 0; p < 4; ++p)
                #pragma unroll
                for (int q = 0; q < 4; ++q)
                    acc[p][q] += a[p] * bb[q];
        }
        #pragma unroll
        for (int p = 0; p < 4; ++p)
            #pragma unroll
            for (int q = 0; q < 4; ++q) {
                int l = ty*4+p, lp = tx*4+q;
                As[l][lp] = (lp <= l) ? acc[p][q] : 0.f;
            }
    }
    __syncthreads();
    // reuse KSs buffer for S_prefix
    const float* Sp = S + (size_t)blockIdx.x * 4096;
    #pragma unroll
    for (int t = 0; t < 16; ++t) {
        int e = tid + t * 256;
        KSs[e >> 6][e & 63] = Sp[e];
    }
    __syncthreads();
    float acc[4][4] = {};
    #pragma unroll 4
    for (int k = 0; k < 64; ++k) {
        float a[4], qq[4], vv[4], sv[4];
        #pragma unroll
        for (int j = 0; j < 4; ++j) {
            a[j]  = As[ty*4+j][k];
            qq[j] = Qs[ty*4+j][k];
            vv[j] = Vs[k][tx*4+j];
            sv[j] = KSs[k][tx*4+j];
        }
        #pragma unroll
        for (int p = 0; p < 4; ++p)
            #pragma unroll
            for (int q = 0; q < 4; ++q)
                acc[p][q] += a[p] * vv[q] + qq[p] * sv[q];
    }
    #pragma unroll
    for (int p = 0; p < 4; ++p)
        #pragma unroll
        for (int q = 0; q < 4; ++q) {
            int l = c*64 + ty*4+p, e = tx*4+q;
            out[((size_t)(b*LL + l) * DD) + h*64 + e] = acc[p][q];
        }
}

extern "C" void kernel_launch(void* const* d_in, const int* in_sizes, int n_in,
                              void* d_out, int out_size, void* d_ws, size_t ws_size,
                              hipStream_t stream) {
    const float* X  = (const float*)d_in[0];
    const float* Wq = (const float*)d_in[1];
    const float* Wv = (const float*)d_in[2];
    const float* qw = (const float*)d_in[3];
    const float* vw = (const float*)d_in[4];
    float* out = (float*)d_out;

    float* Q = (float*)d_ws;                    // B*L*D floats
    float* V = Q + (size_t)BB*LL*DD;            // B*L*D floats
    float* S = V + (size_t)BB*LL*DD;            // B*H*NC*64*64 floats

    dim3 gb(DD/64, (BB*LL)/64, 2);
    gemm_nt<<<gb, 256, 0, stream>>>(X, Wq, Wv, Q, V);
    rmsnorm_k<<<dim3(BB*LL*HH/4, 2), 256, 0, stream>>>(Q, V, qw, vw);
    chunk_kv<<<BB*HH*NC, 256, 0, stream>>>(X, V, S);
    cumsum_k<<<BB*HH, 256, 0, stream>>>(S);
    out_k<<<BB*HH*NC, 256, 0, stream>>>(X, Q, V, S, out);
}

// Round 2
// 143.767 us; speedup vs baseline: 2.0158x; 2.0158x over previous
//
#include <hip/hip_runtime.h>

#define BB 2
#define LL 1024
#define DD 1024
#define HH 16
#define HD 64
#define CH 64
#define NC (LL/CH)
#define EPSF 1e-8f

typedef __attribute__((ext_vector_type(8))) short bf16x8;
typedef __attribute__((ext_vector_type(4))) float f32x4;

static __device__ inline unsigned short f2bf(float f) {
    unsigned int u = __builtin_bit_cast(unsigned int, f);
    u += 0x7fff + ((u >> 16) & 1);     // RNE
    return (unsigned short)(u >> 16);
}

static __device__ inline void gload_lds16(const unsigned short* g, unsigned short* l) {
    __builtin_amdgcn_global_load_lds((const __attribute__((address_space(1))) void*)g,
                                     (__attribute__((address_space(3))) void*)l, 16, 0, 0);
}

// ---------------- fp32 -> bf16 convert: X (2M), Wq (1M), Wv (1M)
__global__ __launch_bounds__(256) void cvt_k(const float* __restrict__ X,
                                             const float* __restrict__ Wq,
                                             const float* __restrict__ Wv,
                                             unsigned short* __restrict__ Xb,
                                             unsigned short* __restrict__ Wqb,
                                             unsigned short* __restrict__ Wvb)
{
    int i = (blockIdx.x * 256 + threadIdx.x) * 4;   // over 4M concatenated elements
    const float* s; unsigned short* d; int off;
    if (i < 2*1024*1024)      { s = X;  d = Xb;  off = i; }
    else if (i < 3*1024*1024) { s = Wq; d = Wqb; off = i - 2*1024*1024; }
    else                      { s = Wv; d = Wvb; off = i - 3*1024*1024; }
    float4 v = *(const float4*)(s + off);
    ushort4 o;
    o.x = f2bf(v.x); o.y = f2bf(v.y); o.z = f2bf(v.z); o.w = f2bf(v.w);
    *(ushort4*)(d + off) = o;
}

// ---------------- bf16 MFMA GEMM: Y[m,n] = sum_k A[m,k] * W[n,k]
// M=2048, N=K=1024. 128x128 tile, BK=32, 256 threads (4 waves, 2x2), 4x4 16x16x32 frags.
__global__ __launch_bounds__(256) void gemm_mfma(const unsigned short* __restrict__ Xb,
                                                 const unsigned short* __restrict__ Wqb,
                                                 const unsigned short* __restrict__ Wvb,
                                                 float* __restrict__ Qr,
                                                 float* __restrict__ Vr)
{
    const int K = DD, N = DD;
    const unsigned short* W = blockIdx.z ? Wvb : Wqb;
    float* Y = blockIdx.z ? Vr : Qr;
    __shared__ unsigned short As[128 * 32];
    __shared__ unsigned short Bs[128 * 32];

    int tid  = threadIdx.x;
    int w    = tid >> 6, lane = tid & 63;
    int quad = lane >> 4, l16 = lane & 15;
    int wm   = w & 1,  wn  = w >> 1;
    int m0   = blockIdx.y * 128, n0 = blockIdx.x * 128;
    int lrow = lane >> 2, lcol = (lane & 3) * 8;

    const unsigned short* gA0 = Xb + (size_t)(m0 + w*16      + lrow) * K + lcol;
    const unsigned short* gA1 = Xb + (size_t)(m0 + (w+4)*16  + lrow) * K + lcol;
    const unsigned short* gB0 = W  + (size_t)(n0 + w*16      + lrow) * K + lcol;
    const unsigned short* gB1 = W  + (size_t)(n0 + (w+4)*16  + lrow) * K + lcol;
    unsigned short* lA0 = &As[w*512];
    unsigned short* lA1 = &As[(w+4)*512];
    unsigned short* lB0 = &Bs[w*512];
    unsigned short* lB1 = &Bs[(w+4)*512];

    f32x4 acc[4][4] = {};

    for (int k0 = 0; k0 < K; k0 += 32) {
        gload_lds16(gA0 + k0, lA0);
        gload_lds16(gA1 + k0, lA1);
        gload_lds16(gB0 + k0, lB0);
        gload_lds16(gB1 + k0, lB1);
        __syncthreads();
        bf16x8 af[4], bfr[4];
        #pragma unroll
        for (int i = 0; i < 4; ++i)
            af[i] = *(const bf16x8*)&As[(wm*64 + i*16 + l16) * 32 + quad*8];
        #pragma unroll
        for (int j = 0; j < 4; ++j)
            bfr[j] = *(const bf16x8*)&Bs[(wn*64 + j*16 + l16) * 32 + quad*8];
        #pragma unroll
        for (int i = 0; i < 4; ++i)
            #pragma unroll
            for (int j = 0; j < 4; ++j)
                acc[i][j] = __builtin_amdgcn_mfma_f32_16x16x32_bf16(af[i], bfr[j], acc[i][j], 0, 0, 0);
        __syncthreads();
    }

    #pragma unroll
    for (int i = 0; i < 4; ++i)
        #pragma unroll
        for (int j = 0; j < 4; ++j)
            #pragma unroll
            for (int r = 0; r < 4; ++r) {
                int row = m0 + wm*64 + i*16 + quad*4 + r;
                int col = n0 + wn*64 + j*16 + l16;
                Y[(size_t)row * N + col] = acc[i][j][r];
            }
}

// ---------------- RMSNorm (in place) over last dim d=64, per-head weight
__global__ __launch_bounds__(256) void rmsnorm_k(float* __restrict__ Q,
                                                 float* __restrict__ V,
                                                 const float* __restrict__ qw,
                                                 const float* __restrict__ vw)
{
    float* Y = (blockIdx.y == 0) ? Q : V;
    const float* w = (blockIdx.y == 0) ? qw : vw;
    int row = blockIdx.x * 4 + (threadIdx.x >> 6);
    int lane = threadIdx.x & 63;
    int h = row % HH;
    size_t idx = (size_t)row * 64 + lane;
    float x = Y[idx];
    float ss = x * x;
    #pragma unroll
    for (int off = 32; off >= 1; off >>= 1) ss += __shfl_xor(ss, off, 64);
    float scale = rsqrtf(ss * (1.0f/64.0f) + EPSF);
    Y[idx] = x * scale * w[h * 64 + lane];
}

// ---------------- per-chunk KV outer-product sums: S_c = K_c^T V_c (64x64)
__global__ __launch_bounds__(256) void chunk_kv(const float* __restrict__ X,
                                                const float* __restrict__ V,
                                                float* __restrict__ S)
{
    int c = blockIdx.x % NC;
    int bh = blockIdx.x / NC;
    int h = bh % HH, b = bh / HH;
    __shared__ float Ks[64][65], Vs[64][65];
    int tid = threadIdx.x;
    #pragma unroll
    for (int t = 0; t < 16; ++t) {
        int e = tid + t * 256;
        int i = e >> 6, j = e & 63;
        size_t base = ((size_t)(b*LL + c*64 + i) * DD) + h*64 + j;
        Ks[i][j] = X[base];
        Vs[i][j] = V[base];
    }
    __syncthreads();
    int tx = tid & 15, ty = tid >> 4;
    float acc[4][4] = {};
    #pragma unroll 8
    for (int i = 0; i < 64; ++i) {
        float a[4], bb[4];
        #pragma unroll
        for (int j = 0; j < 4; ++j) { a[j] = Ks[i][ty*4+j]; bb[j] = Vs[i][tx*4+j]; }
        #pragma unroll
        for (int p = 0; p < 4; ++p)
            #pragma unroll
            for (int q = 0; q < 4; ++q)
                acc[p][q] += a[p] * bb[q];
    }
    float* Sp = S + (size_t)blockIdx.x * 4096;
    #pragma unroll
    for (int p = 0; p < 4; ++p)
        #pragma unroll
        for (int q = 0; q < 4; ++q)
            Sp[(ty*4+p) * 64 + tx*4+q] = acc[p][q];
}

// ---------------- exclusive cumsum of chunk states along chunks (512 blocks)
__global__ __launch_bounds__(256) void cumsum_k(float* __restrict__ S)
{
    int bh = blockIdx.x >> 4;
    int p  = (blockIdx.x & 15) * 256 + threadIdx.x;
    float* base = S + (size_t)bh * NC * 4096 + p;
    float run = 0.f;
    #pragma unroll
    for (int c = 0; c < NC; ++c) {
        float v = base[c * 4096];
        base[c * 4096] = run;
        run += v;
    }
}

// ---------------- out = Q @ S_prefix + tril(Q K^T) @ V, per chunk
__global__ __launch_bounds__(256) void out_k(const float* __restrict__ X,
                                             const float* __restrict__ Q,
                                             const float* __restrict__ V,
                                             const float* __restrict__ S,
                                             float* __restrict__ out)
{
    int c = blockIdx.x % NC;
    int bh = blockIdx.x / NC;
    int h = bh % HH, b = bh / HH;
    __shared__ float Qs[64][65], KSs[64][65], Vs[64][65], As_[64][65];
    int tid = threadIdx.x;
    #pragma unroll
    for (int t = 0; t < 16; ++t) {
        int e = tid + t * 256;
        int i = e >> 6, j = e & 63;
        size_t base = ((size_t)(b*LL + c*64 + i) * DD) + h*64 + j;
        Qs[i][j]  = Q[base];
        KSs[i][j] = X[base];
        Vs[i][j]  = V[base];
    }
    __syncthreads();
    int tx = tid & 15, ty = tid >> 4;
    {
        float acc[4][4] = {};
        #pragma unroll 8
        for (int k = 0; k < 64; ++k) {
            float a[4], bb[4];
            #pragma unroll
            for (int j = 0; j < 4; ++j) { a[j] = Qs[ty*4+j][k]; bb[j] = KSs[tx*4+j][k]; }
            #pragma unroll
            for (int p = 0; p < 4; ++p)
                #pragma unroll
                for (int q = 0; q < 4; ++q)
                    acc[p][q] += a[p] * bb[q];
        }
        #pragma unroll
        for (int p = 0; p < 4; ++p)
            #pragma unroll
            for (int q = 0; q < 4; ++q) {
                int l = ty*4+p, lp = tx*4+q;
                As_[l][lp] = (lp <= l) ? acc[p][q] : 0.f;
            }
    }
    __syncthreads();
    const float* Sp = S + (size_t)blockIdx.x * 4096;
    #pragma unroll
    for (int t = 0; t < 16; ++t) {
        int e = tid + t * 256;
        KSs[e >> 6][e & 63] = Sp[e];
    }
    __syncthreads();
    float acc[4][4] = {};
    #pragma unroll 4
    for (int k = 0; k < 64; ++k) {
        float a[4], qq[4], vv[4], sv[4];
        #pragma unroll
        for (int j = 0; j < 4; ++j) {
            a[j]  = As_[ty*4+j][k];
            qq[j] = Qs[ty*4+j][k];
            vv[j] = Vs[k][tx*4+j];
            sv[j] = KSs[k][tx*4+j];
        }
        #pragma unroll
        for (int p = 0; p < 4; ++p)
            #pragma unroll
            for (int q = 0; q < 4; ++q)
                acc[p][q] += a[p] * vv[q] + qq[p] * sv[q];
    }
    #pragma unroll
    for (int p = 0; p < 4; ++p)
        #pragma unroll
        for (int q = 0; q < 4; ++q) {
            int l = c*64 + ty*4+p, e = tx*4+q;
            out[((size_t)(b*LL + l) * DD) + h*64 + e] = acc[p][q];
        }
}

extern "C" void kernel_launch(void* const* d_in, const int* in_sizes, int n_in,
                              void* d_out, int out_size, void* d_ws, size_t ws_size,
                              hipStream_t stream) {
    const float* X  = (const float*)d_in[0];
    const float* Wq = (const float*)d_in[1];
    const float* Wv = (const float*)d_in[2];
    const float* qw = (const float*)d_in[3];
    const float* vw = (const float*)d_in[4];
    float* out = (float*)d_out;

    float* Q = (float*)d_ws;                    // 2M floats (8 MB)
    float* V = Q + (size_t)BB*LL*DD;            // 2M floats (8 MB)
    float* S = V + (size_t)BB*LL*DD;            // 2M floats (8 MB)

    size_t base_bytes = (size_t)3 * BB*LL*DD * sizeof(float);   // 24 MB
    size_t bf_bytes   = (size_t)4 * 1024 * 1024 * sizeof(unsigned short); // 8 MB
    unsigned short *Xb, *Wqb, *Wvb;
    if (ws_size >= base_bytes + bf_bytes) {
        Xb = (unsigned short*)((char*)d_ws + base_bytes);
    } else {
        // d_out (8 MB) is only written by the final kernel; safe staging area.
        Xb = (unsigned short*)d_out;
    }
    Wqb = Xb  + (size_t)BB*LL*DD;
    Wvb = Wqb + (size_t)DD*DD;

    cvt_k<<<4096, 256, 0, stream>>>(X, Wq, Wv, Xb, Wqb, Wvb);
    dim3 gg(DD/128, (BB*LL)/128, 2);
    gemm_mfma<<<gg, 256, 0, stream>>>(Xb, Wqb, Wvb, Q, V);
    rmsnorm_k<<<dim3(BB*LL*HH/4, 2), 256, 0, stream>>>(Q, V, qw, vw);
    chunk_kv<<<BB*HH*NC, 256, 0, stream>>>(X, V, S);
    cumsum_k<<<BB*HH*NC, 256, 0, stream>>>(S);
    out_k<<<BB*HH*NC, 256, 0, stream>>>(X, Q, V, S, out);
}

// Round 3
// 108.744 us; speedup vs baseline: 2.6650x; 1.3221x over previous
//
#include <hip/hip_runtime.h>

#define BB 2
#define LL 1024
#define DD 1024
#define HH 16
#define NC 16
#define EPSF 1e-8f

typedef __attribute__((ext_vector_type(8))) short bf16x8;
typedef __attribute__((ext_vector_type(4))) float f32x4;
typedef unsigned short u16;

static __device__ inline u16 f2bf(float f) {
    unsigned int u = __builtin_bit_cast(unsigned int, f);
    u += 0x7fff + ((u >> 16) & 1);     // RNE
    return (u16)(u >> 16);
}

static __device__ inline void gload_lds16(const u16* g, u16* l) {
    __builtin_amdgcn_global_load_lds((const __attribute__((address_space(1))) void*)g,
                                     (__attribute__((address_space(3))) void*)l, 16, 0, 0);
}

// ---------------- fp32 -> bf16 convert: X (2M), Wq (1M), Wv (1M)
__global__ __launch_bounds__(256) void cvt_k(const float* __restrict__ X,
                                             const float* __restrict__ Wq,
                                             const float* __restrict__ Wv,
                                             u16* __restrict__ Xb,
                                             u16* __restrict__ Wqb,
                                             u16* __restrict__ Wvb)
{
    int i = (blockIdx.x * 256 + threadIdx.x) * 4;
    const float* s; u16* d; int off;
    if (i < 2*1024*1024)      { s = X;  d = Xb;  off = i; }
    else if (i < 3*1024*1024) { s = Wq; d = Wqb; off = i - 2*1024*1024; }
    else                      { s = Wv; d = Wvb; off = i - 3*1024*1024; }
    float4 v = *(const float4*)(s + off);
    ushort4 o;
    o.x = f2bf(v.x); o.y = f2bf(v.y); o.z = f2bf(v.z); o.w = f2bf(v.w);
    *(ushort4*)(d + off) = o;
}

// ---------------- bf16 MFMA GEMM + fused per-head RMSNorm, bf16 output
// Y[m,n] = rmsnorm_head(sum_k A[m,k]*W[n,k]) ; tile 128(M) x 64(N), BK=32.
// N-tile 64 == one head, so the d=64 norm reduction is block-local.
__global__ __launch_bounds__(256) void gemm_fused(const u16* __restrict__ Xb,
                                                  const u16* __restrict__ Wqb,
                                                  const u16* __restrict__ Wvb,
                                                  const float* __restrict__ qw,
                                                  const float* __restrict__ vw,
                                                  u16* __restrict__ Qb,
                                                  u16* __restrict__ Vb)
{
    const int K = DD, N = DD;
    const u16* W = blockIdx.z ? Wvb : Wqb;
    const float* nw = blockIdx.z ? vw : qw;
    u16* Y = blockIdx.z ? Vb : Qb;
    __shared__ u16 As[128 * 32];
    __shared__ u16 Bs[64 * 32];
    __shared__ float Cs[128][65];

    const int tid = threadIdx.x, w = tid >> 6, lane = tid & 63;
    const int quad = lane >> 4, l16 = lane & 15;
    const int wm = w & 1, wn = w >> 1;
    const int m0 = blockIdx.y * 128, n0 = blockIdx.x * 64;
    const int lrow = lane >> 2, lcol = (lane & 3) * 8;

    const u16* gA0 = Xb + (size_t)(m0 + w*16 + lrow) * K + lcol;
    const u16* gA1 = gA0 + (size_t)64 * K;
    const u16* gB0 = W + (size_t)(n0 + w*16 + lrow) * K + lcol;
    u16* lA0 = &As[(w*16) * 32];
    u16* lA1 = &As[(64 + w*16) * 32];
    u16* lB0 = &Bs[(w*16) * 32];

    f32x4 acc[4][2] = {};
    for (int k0 = 0; k0 < K; k0 += 32) {
        gload_lds16(gA0 + k0, lA0);
        gload_lds16(gA1 + k0, lA1);
        gload_lds16(gB0 + k0, lB0);
        __syncthreads();
        bf16x8 af[4], bf[2];
        #pragma unroll
        for (int i = 0; i < 4; ++i)
            af[i] = *(const bf16x8*)&As[(wm*64 + i*16 + l16) * 32 + quad*8];
        #pragma unroll
        for (int j = 0; j < 2; ++j)
            bf[j] = *(const bf16x8*)&Bs[(wn*32 + j*16 + l16) * 32 + quad*8];
        #pragma unroll
        for (int i = 0; i < 4; ++i)
            #pragma unroll
            for (int j = 0; j < 2; ++j)
                acc[i][j] = __builtin_amdgcn_mfma_f32_16x16x32_bf16(af[i], bf[j], acc[i][j], 0, 0, 0);
        __syncthreads();
    }

    #pragma unroll
    for (int i = 0; i < 4; ++i)
        #pragma unroll
        for (int j = 0; j < 2; ++j)
            #pragma unroll
            for (int r = 0; r < 4; ++r)
                Cs[wm*64 + i*16 + quad*4 + r][wn*32 + j*16 + l16] = acc[i][j][r];
    __syncthreads();

    const int row = tid >> 1, half = tid & 1;
    float vals[32];
    float ss = 0.f;
    #pragma unroll
    for (int c = 0; c < 32; c += 4) {
        float4 v = *(const float4*)&Cs[row][half*32 + c];
        vals[c] = v.x; vals[c+1] = v.y; vals[c+2] = v.z; vals[c+3] = v.w;
        ss += v.x*v.x + v.y*v.y + v.z*v.z + v.w*v.w;
    }
    ss += __shfl_xor(ss, 1, 64);
    const float scale = rsqrtf(ss * (1.f/64.f) + EPSF);
    const float* wp = nw + n0 + half*32;
    u16* yp = Y + (size_t)(m0 + row) * N + n0 + half*32;
    #pragma unroll
    for (int c = 0; c < 32; c += 4) {
        ushort4 o;
        o.x = f2bf(vals[c]   * scale * wp[c]);
        o.y = f2bf(vals[c+1] * scale * wp[c+1]);
        o.z = f2bf(vals[c+2] * scale * wp[c+2]);
        o.w = f2bf(vals[c+3] * scale * wp[c+3]);
        *(ushort4*)(yp + c) = o;
    }
}

// ---------------- per-chunk S^T_c[e][d] = sum_l V[l][e] K[l][d]  via MFMA
__global__ __launch_bounds__(256) void chunk_kv(const u16* __restrict__ Xb,
                                                const u16* __restrict__ Vb,
                                                float* __restrict__ S)
{
    const int c = blockIdx.x & 15, bh = blockIdx.x >> 4;
    const int h = bh & 15, b = bh >> 4;
    __shared__ u16 Kt[64][72];   // [d][l]
    __shared__ u16 Vt[64][72];   // [e][l]
    const int tid = threadIdx.x;
    {
        const int row = tid >> 2, q = tid & 3;   // row = l, q = 16-col group
        size_t gbase = (size_t)(b*LL + c*64 + row) * DD + h*64 + q*16;
        u16 kk[16], vv[16];
        #pragma unroll
        for (int i = 0; i < 16; i += 4) {
            *(ushort4*)&kk[i] = *(const ushort4*)(Xb + gbase + i);
            *(ushort4*)&vv[i] = *(const ushort4*)(Vb + gbase + i);
        }
        #pragma unroll
        for (int i = 0; i < 16; ++i) {
            Kt[q*16 + i][row] = kk[i];
            Vt[q*16 + i][row] = vv[i];
        }
    }
    __syncthreads();
    const int w = tid >> 6, lane = tid & 63, quad = lane >> 4, l16 = lane & 15;
    const int me = (w & 1) * 32, nd = (w >> 1) * 32;
    f32x4 acc[2][2] = {};
    #pragma unroll
    for (int k0 = 0; k0 < 64; k0 += 32) {
        bf16x8 av[2], bv[2];
        #pragma unroll
        for (int i = 0; i < 2; ++i)
            av[i] = *(const bf16x8*)&Vt[me + i*16 + l16][k0 + quad*8];
        #pragma unroll
        for (int j = 0; j < 2; ++j)
            bv[j] = *(const bf16x8*)&Kt[nd + j*16 + l16][k0 + quad*8];
        #pragma unroll
        for (int i = 0; i < 2; ++i)
            #pragma unroll
            for (int j = 0; j < 2; ++j)
                acc[i][j] = __builtin_amdgcn_mfma_f32_16x16x32_bf16(av[i], bv[j], acc[i][j], 0, 0, 0);
    }
    float* Sp = S + (size_t)blockIdx.x * 4096;
    #pragma unroll
    for (int i = 0; i < 2; ++i)
        #pragma unroll
        for (int j = 0; j < 2; ++j)
            #pragma unroll
            for (int r = 0; r < 4; ++r)
                Sp[(me + i*16 + quad*4 + r) * 64 + nd + j*16 + l16] = acc[i][j][r];
}

// ---------------- exclusive cumsum of chunk states along chunks (512 blocks)
__global__ __launch_bounds__(256) void cumsum_k(float* __restrict__ S)
{
    int bh = blockIdx.x >> 4;
    int p  = (blockIdx.x & 15) * 256 + threadIdx.x;
    float* base = S + (size_t)bh * NC * 4096 + p;
    float run = 0.f;
    #pragma unroll
    for (int c = 0; c < NC; ++c) {
        float v = base[c * 4096];
        base[c * 4096] = run;
        run += v;
    }
}

// ---------------- out = tril(Q K^T) @ V + Q @ S0, per chunk, MFMA
__global__ __launch_bounds__(256) void out_k(const u16* __restrict__ Xb,
                                             const u16* __restrict__ Qb,
                                             const u16* __restrict__ Vb,
                                             const float* __restrict__ S,
                                             float* __restrict__ out)
{
    const int c = blockIdx.x & 15, bh = blockIdx.x >> 4;
    const int h = bh & 15, b = bh >> 4;
    __shared__ u16 Qs[64][72];   // [l][d]
    __shared__ u16 Ks[64][72];   // [l'][d]
    __shared__ u16 Vt[64][72];   // [e][l']
    __shared__ u16 St[64][72];   // [e][d]  (S^T prefix, bf16)
    __shared__ u16 Ps[64][72];   // [l][l'] masked P, bf16
    const int tid = threadIdx.x;
    {
        const int row = tid >> 2, q = tid & 3;
        size_t gbase = (size_t)(b*LL + c*64 + row) * DD + h*64 + q*16;
        u16 qv[16], kv[16], vv[16];
        #pragma unroll
        for (int i = 0; i < 16; i += 4) {
            *(ushort4*)&qv[i] = *(const ushort4*)(Qb + gbase + i);
            *(ushort4*)&kv[i] = *(const ushort4*)(Xb + gbase + i);
            *(ushort4*)&vv[i] = *(const ushort4*)(Vb + gbase + i);
        }
        #pragma unroll
        for (int i = 0; i < 16; ++i) {
            Qs[row][q*16 + i] = qv[i];
            Ks[row][q*16 + i] = kv[i];
            Vt[q*16 + i][row] = vv[i];
        }
        const float* sp = S + (size_t)blockIdx.x * 4096 + row*64 + q*16;
        #pragma unroll
        for (int i = 0; i < 16; i += 4) {
            float4 sv = *(const float4*)(sp + i);
            St[row][q*16 + i]     = f2bf(sv.x);
            St[row][q*16 + i + 1] = f2bf(sv.y);
            St[row][q*16 + i + 2] = f2bf(sv.z);
            St[row][q*16 + i + 3] = f2bf(sv.w);
        }
    }
    __syncthreads();
    const int w = tid >> 6, lane = tid & 63, quad = lane >> 4, l16 = lane & 15;
    const int mo = (w & 1) * 32, no = (w >> 1) * 32;

    // P = Q K^T with causal mask, stored bf16 to LDS
    {
        f32x4 pacc[2][2] = {};
        #pragma unroll
        for (int k0 = 0; k0 < 64; k0 += 32) {
            bf16x8 aq[2], bk[2];
            #pragma unroll
            for (int i = 0; i < 2; ++i)
                aq[i] = *(const bf16x8*)&Qs[mo + i*16 + l16][k0 + quad*8];
            #pragma unroll
            for (int j = 0; j < 2; ++j)
                bk[j] = *(const bf16x8*)&Ks[no + j*16 + l16][k0 + quad*8];
            #pragma unroll
            for (int i = 0; i < 2; ++i)
                #pragma unroll
                for (int j = 0; j < 2; ++j)
                    pacc[i][j] = __builtin_amdgcn_mfma_f32_16x16x32_bf16(aq[i], bk[j], pacc[i][j], 0, 0, 0);
        }
        #pragma unroll
        for (int i = 0; i < 2; ++i)
            #pragma unroll
            for (int j = 0; j < 2; ++j)
                #pragma unroll
                for (int r = 0; r < 4; ++r) {
                    int l  = mo + i*16 + quad*4 + r;
                    int lp = no + j*16 + l16;
                    Ps[l][lp] = (lp <= l) ? f2bf(pacc[i][j][r]) : (u16)0;
                }
    }
    __syncthreads();

    // O = P @ V + Q @ S0
    f32x4 acc[2][2] = {};
    #pragma unroll
    for (int k0 = 0; k0 < 64; k0 += 32) {
        bf16x8 a1[2], b1[2], a2[2], b2[2];
        #pragma unroll
        for (int i = 0; i < 2; ++i) {
            a1[i] = *(const bf16x8*)&Ps[mo + i*16 + l16][k0 + quad*8];
            a2[i] = *(const bf16x8*)&Qs[mo + i*16 + l16][k0 + quad*8];
        }
        #pragma unroll
        for (int j = 0; j < 2; ++j) {
            b1[j] = *(const bf16x8*)&Vt[no + j*16 + l16][k0 + quad*8];
            b2[j] = *(const bf16x8*)&St[no + j*16 + l16][k0 + quad*8];
        }
        #pragma unroll
        for (int i = 0; i < 2; ++i)
            #pragma unroll
            for (int j = 0; j < 2; ++j) {
                acc[i][j] = __builtin_amdgcn_mfma_f32_16x16x32_bf16(a1[i], b1[j], acc[i][j], 0, 0, 0);
                acc[i][j] = __builtin_amdgcn_mfma_f32_16x16x32_bf16(a2[i], b2[j], acc[i][j], 0, 0, 0);
            }
    }
    float* op = out + (size_t)(b*LL + c*64) * DD + h*64;
    #pragma unroll
    for (int i = 0; i < 2; ++i)
        #pragma unroll
        for (int j = 0; j < 2; ++j)
            #pragma unroll
            for (int r = 0; r < 4; ++r)
                op[(size_t)(mo + i*16 + quad*4 + r) * DD + no + j*16 + l16] = acc[i][j][r];
}

extern "C" void kernel_launch(void* const* d_in, const int* in_sizes, int n_in,
                              void* d_out, int out_size, void* d_ws, size_t ws_size,
                              hipStream_t stream) {
    const float* X  = (const float*)d_in[0];
    const float* Wq = (const float*)d_in[1];
    const float* Wv = (const float*)d_in[2];
    const float* qw = (const float*)d_in[3];
    const float* vw = (const float*)d_in[4];
    float* out = (float*)d_out;

    u16* Xb  = (u16*)d_ws;                       // 2M u16
    u16* Wqb = Xb  + (size_t)2*1024*1024;        // 1M
    u16* Wvb = Wqb + (size_t)1024*1024;          // 1M
    u16* Qb  = Wvb + (size_t)1024*1024;          // 2M
    u16* Vb  = Qb  + (size_t)2*1024*1024;        // 2M
    float* S = (float*)(Vb + (size_t)2*1024*1024); // 2M floats

    cvt_k<<<4096, 256, 0, stream>>>(X, Wq, Wv, Xb, Wqb, Wvb);
    gemm_fused<<<dim3(16, 16, 2), 256, 0, stream>>>(Xb, Wqb, Wvb, qw, vw, Qb, Vb);
    chunk_kv<<<BB*HH*NC, 256, 0, stream>>>(Xb, Vb, S);
    cumsum_k<<<BB*HH*NC, 256, 0, stream>>>(S);
    out_k<<<BB*HH*NC, 256, 0, stream>>>(Xb, Qb, Vb, S, out);
}